// Round 22
// baseline (123.316 us; speedup 1.0000x reference)
//
#include <hip/hip_runtime.h>
#include <stdint.h>

#define NB 2
#define NS 2048
#define ND 1024
#define NH 16
#define NHD 64
#define NM (NB*NS)   // 4096

typedef __bf16 bf16;
typedef float f32x4 __attribute__((ext_vector_type(4)));
typedef __bf16 bf16x8 __attribute__((ext_vector_type(8)));
typedef __bf16 bf16x4 __attribute__((ext_vector_type(4)));

#define MFMA16(a,b,c) __builtin_amdgcn_mfma_f32_16x16x32_bf16(a,b,c,0,0,0)

__device__ __forceinline__ void gld_lds16(const bf16* g, bf16* l) {
  __builtin_amdgcn_global_load_lds((const __attribute__((address_space(1))) void*)g,
                                   (__attribute__((address_space(3))) void*)l,
                                   16, 0, 0);
}

// Barrier that drains LDS ops but leaves global loads in flight (vmcnt
// untouched) — unlike __syncthreads(), which drains vmcnt(0).
__device__ __forceinline__ void block_sync_lds() {
  asm volatile("s_waitcnt lgkmcnt(0)\n\ts_barrier" ::: "memory");
}

// ---------------- fp32 -> bf16 conversion, 4 weight matrices --------------
__global__ __launch_bounds__(256)
void cvt_w4(const float* __restrict__ s0, const float* __restrict__ s1,
            const float* __restrict__ s2, const float* __restrict__ s3,
            bf16* __restrict__ dst, int n4each) {
  const int t = blockIdx.y;
  const float* s = (t == 0) ? s0 : (t == 1) ? s1 : (t == 2) ? s2 : s3;
  int i = blockIdx.x * blockDim.x + threadIdx.x;
  if (i >= n4each) return;
  float4 v = ((const float4*)s)[i];
  bf16x4 o = { (bf16)v.x, (bf16)v.y, (bf16)v.z, (bf16)v.w };
  ((bf16x4*)(dst + (size_t)t * n4each * 4))[i] = o;
}

// ---------------- QKV projection GEMM, fused fp32->bf16 on A --------------
// attn_k-style one-barrier depth-1 prefetch pipeline (r12/r16-proven):
// per iter {top: issue B(t+1) gld_lds -> Bs[buf^1], issue A(t+1) fp32 loads
// -> regs} -> compute on buf -> {writeA(buf^1): cvt + ds_write; its register
// wait drains the B(t+1) DMA too, since B was issued BEFORE A on the single
// in-order vmcnt} -> block_sync_lds. Load-to-use distance = one compute
// phase (~1300cy) >> HBM latency. r21's failure was SYNCHRONOUS reg-staging
// (load and consume in the same interval) — this fixes exactly that.
// T2 swizzle: A ds_writes land in swizzled slots; B source pre-swizzled.
// 128x64 tile, grid 1536; fused RoPE (t<2); q scaled by (1/sqrt(HD))*log2e;
// t<2 -> bf16 scatter [B,H,S,HD]; t==2 (V) -> DIRECT [BH,HD,S] transpose.
__global__ __launch_bounds__(256)
void gemm_qkv(const float* __restrict__ Qf, const float* __restrict__ Kf,
              const float* __restrict__ Vf, const bf16* __restrict__ W,
              const float* __restrict__ b0, const float* __restrict__ b1,
              const float* __restrict__ b2,
              const float* __restrict__ fc, const float* __restrict__ fs,
              bf16* __restrict__ obf, bf16* __restrict__ vtp) {
  constexpr int K = ND;
  __shared__ __align__(16) bf16 As[2][128 * 64];   // 32 KB
  __shared__ __align__(16) bf16 Bs[2][64 * 64];    // 16 KB
  const int tid = threadIdx.x;
  const int w = tid >> 6, lane = tid & 63;

  // XCD-bijective block decode (hardware round-robins linear id % 8)
  const int id = blockIdx.x;
  const int xcd = id & 7, r = id >> 3;        // r 0..191
  const int t = r >> 6;                       // tensor 0..2
  const int rem = r & 63;
  const int nt = rem & 15;                    // 0..15
  const int mt = xcd + 8 * (rem >> 4);        // 0..31

  const float* Ab = (t == 0) ? Qf : (t == 1) ? Kf : Vf;
  const bf16* Wb = W + (size_t)t * ((size_t)ND * K);
  const float* bias = (t == 0) ? b0 : (t == 1) ? b1 : b2;
  const int wr = (w >> 1) * 64, wc = (w & 1) * 32;
  f32x4 acc[4][2] = {};

  // staging thread mapping
  const int srow = w * 8 + (lane >> 3);       // 0..31 ; srow&7 == (lane>>3)&7
  const int scol = (lane & 7) * 8;            // linear fp32 col
  const int swz  = (((lane & 7) ^ ((lane >> 3) & 7)) << 3);   // T2 slot
  const float* ga = Ab + (size_t)(mt * 128 + srow) * K + scol;
  const bf16* gb = Wb + (size_t)(nt * 64 + srow) * K + swz;   // pre-swizzled

  f32x4 ar[4][2];   // A prefetch (constant-indexed local -> registers)
  auto issueB = [&](int k0, int buf) {
#pragma unroll
    for (int it = 0; it < 2; ++it)
      gld_lds16(gb + (size_t)(it * 32) * K + k0, &Bs[buf][(it * 4 + w) * 512]);
  };
  auto loadA = [&](int k0) {
#pragma unroll
    for (int it = 0; it < 4; ++it) {
      const float* p = ga + (size_t)(it * 32) * K + k0;
      ar[it][0] = *(const f32x4*)p;
      ar[it][1] = *(const f32x4*)(p + 4);
    }
  };
  auto writeA = [&](int buf) {   // register wait here drains older B DMA too
#pragma unroll
    for (int it = 0; it < 4; ++it) {
      bf16x8 v8 = { (bf16)ar[it][0][0], (bf16)ar[it][0][1],
                    (bf16)ar[it][0][2], (bf16)ar[it][0][3],
                    (bf16)ar[it][1][0], (bf16)ar[it][1][1],
                    (bf16)ar[it][1][2], (bf16)ar[it][1][3] };
      *(bf16x8*)&As[buf][(it * 32 + srow) * 64 + swz] = v8;
    }
  };

  // prologue: stage tile 0 (B DMA issued first; writeA's wait drains it)
  issueB(0, 0);
  loadA(0);
  writeA(0);
  block_sync_lds();

  for (int kt = 0; kt < 16; ++kt) {
    const int buf = kt & 1;
    if (kt + 1 < 16) {
      issueB((kt + 1) * 64, buf ^ 1);   // buf^1 readers synced at prev barrier
      loadA((kt + 1) * 64);             // A newest -> writeA wait drains B too
    }

#pragma unroll
    for (int ks = 0; ks < 2; ++ks) {
      bf16x8 af[4], bfr[2];
#pragma unroll
      for (int i = 0; i < 4; ++i) {
        const int row = wr + i * 16 + (lane & 15);     // row&7 == lane&7
        af[i] = *(const bf16x8*)&As[buf][row * 64 +
                 (((ks * 4 + (lane >> 4)) ^ (lane & 7)) << 3)];
      }
#pragma unroll
      for (int j = 0; j < 2; ++j) {
        const int row = wc + j * 16 + (lane & 15);
        bfr[j] = *(const bf16x8*)&Bs[buf][row * 64 +
                  (((ks * 4 + (lane >> 4)) ^ (lane & 7)) << 3)];
      }
#pragma unroll
      for (int i = 0; i < 4; ++i)
#pragma unroll
        for (int j = 0; j < 2; ++j)
          acc[i][j] = MFMA16(af[i], bfr[j], acc[i][j]);
    }

    if (kt + 1 < 16) writeA(buf ^ 1);   // cvt + ds_write next tile
    block_sync_lds();                   // publish; guards WAR for next iter
  }

#pragma unroll
  for (int i = 0; i < 4; ++i) {
#pragma unroll
    for (int j = 0; j < 2; ++j) {
      const int gcol = nt * 64 + wc + j * 16 + (lane & 15);
      const float bv = bias[gcol];
      if (t == 2) {
        // V: write transposed [BH, HD, S] directly (4 consecutive s / lane)
        const int s0g = mt * 128 + wr + i * 16 + (lane >> 4) * 4;
        const int b = s0g >> 11, s = s0g & (NS - 1);
        const int h = gcol >> 6, hd = gcol & 63;
        bf16x4 pk = { (bf16)(acc[i][j][0] + bv), (bf16)(acc[i][j][1] + bv),
                      (bf16)(acc[i][j][2] + bv), (bf16)(acc[i][j][3] + bv) };
        *(bf16x4*)&vtp[((size_t)(b * NH + h) * NHD + hd) * NS + s] = pk;
        continue;
      }
#pragma unroll
      for (int r4 = 0; r4 < 4; ++r4) {
        const int grow = mt * 128 + wr + i * 16 + (lane >> 4) * 4 + r4;
        float v = acc[i][j][r4] + bv;
        const int b = grow >> 11, s = grow & (NS - 1);
        const int h = gcol >> 6, hd = gcol & 63;
        // fused RoPE: lane pairs hold adjacent hd columns
        float pv = __shfl_xor(v, 1);
        const int ii = hd >> 1;
        float c  = fc[(s << 5) + ii];
        float sn = fs[(s << 5) + ii];
        v = ((hd & 1) == 0) ? (v * c - pv * sn) : (pv * sn + v * c);
        if (t == 0) v *= 0.18033688011112042f;   // (1/sqrt(HD)) * log2(e)
        obf[(size_t)t * ((size_t)NM * ND) +
            (((size_t)(b * NH + h) * NS + s) * NHD + hd)] = (bf16)v;
      }
    }
  }
}

// ---------------- out-projection GEMM (2-phase + T2 swizzle), 64x64 -------
__global__ __launch_bounds__(256)
void gemm_out(const bf16* __restrict__ A, const bf16* __restrict__ W,
              const float* __restrict__ b0, float* __restrict__ of) {
  constexpr int K = ND;
  __shared__ __align__(16) bf16 As[64 * 64];
  __shared__ __align__(16) bf16 Bs[64 * 64];
  const int tid = threadIdx.x;
  const int w = tid >> 6, lane = tid & 63;

  const int id = blockIdx.x;
  const int xcd = id & 7, r = id >> 3;
  const int nt = r & 15;
  const int mt = xcd + 8 * (r >> 4);

  const int wr = (w >> 1) * 32, wc = (w & 1) * 32;
  f32x4 acc[2][2] = {};

  const int swsrc = (((lane & 7) ^ ((lane >> 3) & 7)) << 3);
  const bf16* ga = A + (size_t)(mt * 64 + w * 8 + (lane >> 3)) * K + swsrc;
  const bf16* gb = W + (size_t)(nt * 64 + w * 8 + (lane >> 3)) * K + swsrc;

  for (int k0 = 0; k0 < K; k0 += 64) {
    __syncthreads();
#pragma unroll
    for (int it = 0; it < 2; ++it)
      gld_lds16(ga + (size_t)(it * 32) * K + k0, As + (it * 4 + w) * 512);
#pragma unroll
    for (int it = 0; it < 2; ++it)
      gld_lds16(gb + (size_t)(it * 32) * K + k0, Bs + (it * 4 + w) * 512);
    __syncthreads();

#pragma unroll
    for (int ks = 0; ks < 2; ++ks) {
      bf16x8 af[2], bfr[2];
#pragma unroll
      for (int i = 0; i < 2; ++i) {
        const int row = wr + i * 16 + (lane & 15);
        af[i] = *(const bf16x8*)&As[row * 64 +
                 (((ks * 4 + (lane >> 4)) ^ (lane & 7)) << 3)];
      }
#pragma unroll
      for (int j = 0; j < 2; ++j) {
        const int row = wc + j * 16 + (lane & 15);
        bfr[j] = *(const bf16x8*)&Bs[row * 64 +
                  (((ks * 4 + (lane >> 4)) ^ (lane & 7)) << 3)];
      }
#pragma unroll
      for (int i = 0; i < 2; ++i)
#pragma unroll
        for (int j = 0; j < 2; ++j)
          acc[i][j] = MFMA16(af[i], bfr[j], acc[i][j]);
    }
  }

#pragma unroll
  for (int i = 0; i < 2; ++i) {
#pragma unroll
    for (int j = 0; j < 2; ++j) {
      const int gcol = nt * 64 + wc + j * 16 + (lane & 15);
      const float bv = b0[gcol];
#pragma unroll
      for (int r4 = 0; r4 < 4; ++r4) {
        const int grow = mt * 64 + wr + i * 16 + (lane >> 4) * 4 + r4;
        of[(size_t)grow * ND + gcol] = acc[i][j][r4] + bv;
      }
    }
  }
}

// ---------------- one 64-k-tile step for a 16-row q-subtile ---------------
// K/V/P in XOR-swizzled [*][64] LDS (chunk8 ^= row&7). Defer-max (T13).
__device__ __forceinline__ void attn_tile(
    const bf16* __restrict__ Ksh, const bf16* __restrict__ Vsh,
    bf16* __restrict__ Pw, const bf16x8* qf, f32x4* o,
    float& m, float& l, int qi, int kk0, bool diag, int qrow, int grp) {
  const int s7 = qrow & 7;
  f32x4 sc[4] = {};
  __builtin_amdgcn_s_setprio(1);
#pragma unroll
  for (int ch = 0; ch < 2; ++ch)
#pragma unroll
    for (int cb = 0; cb < 4; ++cb) {
      bf16x8 kf = *(const bf16x8*)
        &Ksh[(cb * 16 + qrow) * 64 + (((ch * 4 + grp) ^ s7) << 3)];
      sc[cb] = MFMA16(kf, qf[ch], sc[cb]);   // S^T[k][q]
    }
  __builtin_amdgcn_s_setprio(0);

  if (diag) {
#pragma unroll
    for (int cb = 0; cb < 4; ++cb)
#pragma unroll
      for (int r = 0; r < 4; ++r)
        if (kk0 + cb * 16 + grp * 4 + r > qi) sc[cb][r] = -1e30f;
  }

  float a0 = fmaxf(fmaxf(sc[0][0], sc[0][1]), fmaxf(sc[0][2], sc[0][3]));
  float a1 = fmaxf(fmaxf(sc[1][0], sc[1][1]), fmaxf(sc[1][2], sc[1][3]));
  float a2 = fmaxf(fmaxf(sc[2][0], sc[2][1]), fmaxf(sc[2][2], sc[2][3]));
  float a3 = fmaxf(fmaxf(sc[3][0], sc[3][1]), fmaxf(sc[3][2], sc[3][3]));
  float pm = fmaxf(fmaxf(a0, a1), fmaxf(a2, a3));

  if (__any(pm > m + 8.f)) {     // defer-max: rescale only when needed
    float px = fmaxf(pm, __shfl_xor(pm, 16));
    px = fmaxf(px, __shfl_xor(px, 32));
    const float mn = fmaxf(m, px);
    const float scl = exp2f(m - mn);
    m = mn;
    l *= scl;
#pragma unroll
    for (int hb = 0; hb < 4; ++hb)
#pragma unroll
      for (int r = 0; r < 4; ++r) o[hb][r] *= scl;
  }

#pragma unroll
  for (int cb = 0; cb < 4; ++cb) {
    bf16x4 pk;
#pragma unroll
    for (int r = 0; r < 4; ++r) {
      float p = exp2f(sc[cb][r] - m);
      l += p;
      pk[r] = (bf16)p;
    }
    *(bf16x4*)&Pw[qrow * 64 + (((((cb << 1) | (grp >> 1)) ^ s7) << 3)) +
                  ((grp & 1) << 2)] = pk;
  }

  __builtin_amdgcn_s_setprio(1);
#pragma unroll
  for (int ch = 0; ch < 2; ++ch) {
    bf16x8 pa = *(const bf16x8*)
      &Pw[qrow * 64 + (((ch * 4 + grp) ^ s7) << 3)];
#pragma unroll
    for (int hb = 0; hb < 4; ++hb) {
      bf16x8 vf = *(const bf16x8*)
        &Vsh[(hb * 16 + qrow) * 64 + (((ch * 4 + grp) ^ s7) << 3)];
      o[hb] = MFMA16(vf, pa, o[hb]);         // O^T[hd][q]
    }
  }
  __builtin_amdgcn_s_setprio(0);
}

// ---------------- flash attention, causal, 8 waves, k-parity split -------
// r12/r16-proven: double-buffered group-private K/V -> ONE barrier per
// round; XOR-swizzled unpadded LDS (80 KB, 2 blocks/CU); defer-max softmax;
// uniform 17/16-round worklists. grid (32, 16): x = bh, y = j.
// HARD CONSTRAINTS (r13/r15/r17/r19): at (512,4) VGPR cap = 64, exactly
// filled; added live state spills. (512,2) avoids spill but regressed.
// V must flow through the staged-prefetch path (in-round awaited global
// loads drain the K-prefetch vmcnt pipeline).
__global__ __launch_bounds__(512, 4)
void attn_k(const bf16* __restrict__ q, const bf16* __restrict__ k,
            const bf16* __restrict__ vt, bf16* __restrict__ out) {
  __shared__ __align__(16) char smem[81920];
  bf16* KV = (bf16*)smem;                          // [group][buf][K/V][64*64]
  bf16* Pr = (bf16*)(smem + 65536);                // [8 waves][16*64]
  auto MO = (float(*)[2][16][68])smem;             // overlay [4][2][16][68] f32
  auto ML = (float(*)[2][16][2])(smem + 36864);    // overlay [4][2][16][2] f32

  const int tid = threadIdx.x;
  const int w = tid >> 6, lane = tid & 63;
  const int h = w >> 2, wl = w & 3;                // group, pair-index
  const int qrow = lane & 15, grp = lane >> 4;
  const int bh = blockIdx.x, j = blockIdx.y;
  const int b = bh >> 4, hh = bh & (NH - 1);
  const int tA = j, tB = 31 - j;

  const bf16* qb = q + (size_t)bh * NS * NHD;
  const bf16* kb = k + (size_t)bh * NS * NHD;
  const bf16* vb = vt + (size_t)bh * NHD * NS;

  const int nA = (j >= h) ? (((j - h) >> 1) + 1) : 0;   // group's tile-A rounds
  const int nB = (((31 - j) - h) >> 1) + 1;             // group's tile-B rounds
  const int len = nA + nB;                              // 17 (h=0) or 16 (h=1)

  const int q0A = tA * 64 + wl * 16, q0B = tB * 64 + wl * 16;
  bf16x8 qfA[2], qfB[2];
#pragma unroll
  for (int ch = 0; ch < 2; ++ch) {
    qfA[ch] = *(const bf16x8*)&qb[(size_t)(q0A + qrow) * NHD + ch * 32 + grp * 8];
    qfB[ch] = *(const bf16x8*)&qb[(size_t)(q0B + qrow) * NHD + ch * 32 + grp * 8];
  }

  f32x4 oA[4] = {}, oB[4] = {};
  float mA = -1e30f, lA = 0.f, mB = -1e30f, lB = 0.f;

  // group-private staging slots: 256 threads cover 64x64 K + 64x64 V
  const int local = tid & 255;
  const int r0 = local >> 3;                     // rows r0, r0+32
  const int c0 = (local & 7) * 8;                // linear global col
  const int sw = (((local & 7) ^ (r0 & 7)) << 3);  // swizzled LDS col

  bf16* Pw = Pr + w * 1024;
  auto Kb = [&](int buf) { return KV + ((h * 2 + buf) * 2 + 0) * 4096; };
  auto Vb = [&](int buf) { return KV + ((h * 2 + buf) * 2 + 1) * 4096; };

  bf16x8 ka0, ka1, va0, va1;
  auto load_round = [&](int r) {
    const bool isA = r < nA;
    const int kt = isA ? (h + 2 * r) : (h + 2 * (r - nA));
    const int kk0 = kt * 64;
    ka0 = *(const bf16x8*)&kb[(size_t)(kk0 + r0) * NHD + c0];
    ka1 = *(const bf16x8*)&kb[(size_t)(kk0 + r0 + 32) * NHD + c0];
    va0 = *(const bf16x8*)&vb[(size_t)r0 * NS + kk0 + c0];
    va1 = *(const bf16x8*)&vb[(size_t)(r0 + 32) * NS + kk0 + c0];
  };
  auto store_tile = [&](int buf) {
    bf16* Ksc = Kb(buf);
    bf16* Vsc = Vb(buf);
    *(bf16x8*)&Ksc[r0 * 64 + sw]        = ka0;
    *(bf16x8*)&Ksc[(r0 + 32) * 64 + sw] = ka1;   // (r0+32)&7 == r0&7
    *(bf16x8*)&Vsc[r0 * 64 + sw]        = va0;
    *(bf16x8*)&Vsc[(r0 + 32) * 64 + sw] = va1;
  };

  // prologue: tile 0 -> buf 0; issue tile-1 loads
  load_round(0);
  store_tile(0);
  load_round(1);           // len >= 16 always
  block_sync_lds();        // publish buf0 (global loads stay in flight)

  for (int r = 0; r < 17; ++r) {
    const int cur = r & 1;
    const bool act = r < len;
    if (r + 1 < len) store_tile(cur ^ 1);   // tile r+1; its readers synced at r-1
    if (r + 2 < len) load_round(r + 2);     // issue next loads under compute
    if (act) {
      const bool isA = r < nA;
      const int kt = isA ? (h + 2 * r) : (h + 2 * (r - nA));
      if (isA)
        attn_tile(Kb(cur), Vb(cur), Pw, qfA, oA, mA, lA,
                  q0A + qrow, kt * 64, kt == tA, qrow, grp);
      else
        attn_tile(Kb(cur), Vb(cur), Pw, qfB, oB, mB, lB,
                  q0B + qrow, kt * 64, kt == tB, qrow, grp);
    }
    block_sync_lds();      // single barrier: publishes writes, guards WAR
  }

  // reduce l across the 4 lane-groups sharing each q-row
  lA += __shfl_xor(lA, 16); lA += __shfl_xor(lA, 32);
  lB += __shfl_xor(lB, 16); lB += __shfl_xor(lB, 32);

  __syncthreads();   // all LDS traffic done before overlay reuse

  if (h == 1) {      // publish group-1 partials (fp32)
#pragma unroll
    for (int hb = 0; hb < 4; ++hb) {
      *(f32x4*)&MO[wl][0][qrow][hb * 16 + grp * 4] = oA[hb];
      *(f32x4*)&MO[wl][1][qrow][hb * 16 + grp * 4] = oB[hb];
    }
    if (grp == 0) {
      ML[wl][0][qrow][0] = mA; ML[wl][0][qrow][1] = lA;
      ML[wl][1][qrow][0] = mB; ML[wl][1][qrow][1] = lB;
    }
  }
  __syncthreads();

  if (h == 0) {      // merge + store
#pragma unroll
    for (int sub = 0; sub < 2; ++sub) {
      const float m0 = sub ? mB : mA, l0 = sub ? lB : lA;
      const f32x4* o0 = sub ? oB : oA;
      const float m1 = ML[wl][sub][qrow][0], l1 = ML[wl][sub][qrow][1];
      const float mm = fmaxf(m0, m1);
      const float s0 = exp2f(m0 - mm), s1 = exp2f(m1 - mm);
      const float inv = 1.f / (l0 * s0 + l1 * s1);
      const int s = (sub ? q0B : q0A) + qrow;
      bf16* op = out + (size_t)(b * NS + s) * ND + hh * NHD + grp * 4;
#pragma unroll
      for (int hb = 0; hb < 4; ++hb) {
        f32x4 o1 = *(const f32x4*)&MO[wl][sub][qrow][hb * 16 + grp * 4];
        bf16x4 ov = { (bf16)((o0[hb][0] * s0 + o1[0] * s1) * inv),
                      (bf16)((o0[hb][1] * s0 + o1[1] * s1) * inv),
                      (bf16)((o0[hb][2] * s0 + o1[2] * s1) * inv),
                      (bf16)((o0[hb][3] * s0 + o1[3] * s1) * inv) };
        *(bf16x4*)&op[hb * 16] = ov;
      }
    }
  }
}

// -------------------------------------------------------------------------
extern "C" void kernel_launch(void* const* d_in, const int* in_sizes, int n_in,
                              void* d_out, int out_size, void* d_ws, size_t ws_size,
                              hipStream_t stream) {
  const float* Q  = (const float*)d_in[0];
  const float* K  = (const float*)d_in[1];
  const float* V  = (const float*)d_in[2];
  // d_in[3] = mask (causal, known analytically -> unused)
  const float* fc = (const float*)d_in[4];
  const float* fs = (const float*)d_in[5];
  const float* wq = (const float*)d_in[6];
  const float* bq = (const float*)d_in[7];
  const float* wk = (const float*)d_in[8];
  const float* bk = (const float*)d_in[9];
  const float* wv = (const float*)d_in[10];
  const float* bv = (const float*)d_in[11];
  const float* wo = (const float*)d_in[12];
  const float* bo = (const float*)d_in[13];
  float* out = (float*)d_out;
  bf16* ws = (bf16*)d_ws;

  const size_t MB_ = 1024 * 1024;  // elements
  bf16* Wqkv = ws + 12 * MB_;          // 3 x 1M (wq, wk, wv)
  bf16* Wo   = ws + 15 * MB_;          // 1M
  bf16* qp   = ws + 16 * MB_;          // q' [BH,S,HD] 4M
  bf16* kp   = ws + 20 * MB_;          // k' 4M
  bf16* vtp  = ws + 28 * MB_;          // v transposed [BH,HD,S] 4M (direct)
  bf16* aout = ws + 32 * MB_;          // attention output [M, D] 4M

  cvt_w4<<<dim3(1024, 4), 256, 0, stream>>>(wq, wk, wv, wo, Wqkv, 262144);

  gemm_qkv<<<1536, 256, 0, stream>>>(Q, K, V, Wqkv, bq, bk, bv, fc, fs,
                                     qp, vtp);

  attn_k<<<dim3(32, 16), 512, 0, stream>>>(qp, kp, vtp, aout);

  gemm_out<<<1024, 256, 0, stream>>>(aout, Wo, bo, out);
}

// Round 23
// 116.313 us; speedup vs baseline: 1.0602x; 1.0602x over previous
//
#include <hip/hip_runtime.h>
#include <stdint.h>

#define NB 2
#define NS 2048
#define ND 1024
#define NH 16
#define NHD 64
#define NM (NB*NS)   // 4096

typedef __bf16 bf16;
typedef float f32x4 __attribute__((ext_vector_type(4)));
typedef __bf16 bf16x8 __attribute__((ext_vector_type(8)));
typedef __bf16 bf16x4 __attribute__((ext_vector_type(4)));

#define MFMA16(a,b,c) __builtin_amdgcn_mfma_f32_16x16x32_bf16(a,b,c,0,0,0)

__device__ __forceinline__ void gld_lds16(const bf16* g, bf16* l) {
  __builtin_amdgcn_global_load_lds((const __attribute__((address_space(1))) void*)g,
                                   (__attribute__((address_space(3))) void*)l,
                                   16, 0, 0);
}

// Barrier that drains LDS ops but leaves global loads in flight (vmcnt
// untouched) — unlike __syncthreads(), which drains vmcnt(0).
__device__ __forceinline__ void block_sync_lds() {
  asm volatile("s_waitcnt lgkmcnt(0)\n\ts_barrier" ::: "memory");
}

// ---------------- fp32 -> bf16 conversion, all 7 tensors ------------------
__global__ __launch_bounds__(256)
void cvt7(const float* __restrict__ s0, const float* __restrict__ s1,
          const float* __restrict__ s2, const float* __restrict__ s3,
          const float* __restrict__ s4, const float* __restrict__ s5,
          const float* __restrict__ s6, bf16* __restrict__ dst) {
  const int t = blockIdx.y;
  const float* s = (t == 0) ? s0 : (t == 1) ? s1 : (t == 2) ? s2 :
                   (t == 3) ? s3 : (t == 4) ? s4 : (t == 5) ? s5 : s6;
  const int n4 = (t < 3) ? (1 << 20) : (1 << 18);
  const size_t eoff = (t < 3) ? ((size_t)t << 22) : ((size_t)12 << 20) + ((size_t)(t - 3) << 20);
  int i = blockIdx.x * blockDim.x + threadIdx.x;
  if (i >= n4) return;
  float4 v = ((const float4*)s)[i];
  bf16x4 o = { (bf16)v.x, (bf16)v.y, (bf16)v.z, (bf16)v.w };
  ((bf16x4*)(dst + eoff))[i] = o;
}

// ---------------- NT GEMM (2-phase + T2 swizzle) --------------------------
// MODE 0: QKV projection, 128x64 tile, grid 1536 (~6 blocks/CU); fused RoPE
//         (t<2); q scaled by (1/sqrt(HD))*log2(e); t<2 -> bf16 scatter
//         [B,H,S,HD]; t==2 (V) -> DIRECT [BH,HD,S] transposed write.
// MODE 1: output projection, 64x64 tile, grid 1024 (4 blocks/CU), fp32 out.
// NOTE (r21/r22): fusing the Q/K/V fp32->bf16 cvt into A-staging regressed
// both synchronously (r21, latency exposed) and pipelined (r22, compiler
// sinks the fp32 loads' waitcnt; 48 KB LDS cuts co-residency). Keep cvt7.
template<int MODE>
__global__ __launch_bounds__(256)
void gemm_nt(const bf16* __restrict__ A, const bf16* __restrict__ W,
             const float* __restrict__ b0, const float* __restrict__ b1,
             const float* __restrict__ b2,
             const float* __restrict__ fc, const float* __restrict__ fs,
             bf16* __restrict__ obf, bf16* __restrict__ vtp,
             float* __restrict__ of) {
  constexpr int K = ND;
  constexpr int BM = (MODE == 0) ? 128 : 64;
  constexpr int BN = 64;
  constexpr int MI = (MODE == 0) ? 4 : 2;      // M-fragments per wave
  constexpr int NJ = 2;                        // N-fragments per wave
  constexpr int ITA = (MODE == 0) ? 4 : 2;     // A staging chunks
  constexpr int ITB = 2;                       // B staging chunks
  __shared__ __align__(16) bf16 As[BM * 64];
  __shared__ __align__(16) bf16 Bs[BN * 64];
  const int tid = threadIdx.x;
  const int w = tid >> 6, lane = tid & 63;

  // XCD-bijective block decode (hardware round-robins linear id % 8)
  const int id = blockIdx.x;
  const int xcd = id & 7, r = id >> 3;
  int t, nt, mt;
  if (MODE == 0) { t = r >> 6; const int rem = r & 63; nt = rem & 15; mt = xcd + 8 * (rem >> 4); }
  else           { t = 0;                              nt = r & 15;   mt = xcd + 8 * (r >> 4);   }

  const bf16* Ab = A + (size_t)t * ((size_t)NM * K);
  const bf16* Wb = W + (size_t)t * ((size_t)ND * K);
  const float* bias = (t == 0) ? b0 : (t == 1) ? b1 : b2;
  const int wr = (w >> 1) * (BM / 2), wc = (w & 1) * 32;
  f32x4 acc[MI][NJ] = {};

  // T2: source col-chunk pre-swizzled by row&7; LDS dest stays linear (DMA).
  const int swsrc = (((lane & 7) ^ ((lane >> 3) & 7)) << 3);
  const bf16* ga = Ab + (size_t)(mt * BM + w * 8 + (lane >> 3)) * K + swsrc;
  const bf16* gb = Wb + (size_t)(nt * BN + w * 8 + (lane >> 3)) * K + swsrc;

  for (int k0 = 0; k0 < K; k0 += 64) {
    __syncthreads();   // readers of previous tile done
#pragma unroll
    for (int it = 0; it < ITA; ++it)
      gld_lds16(ga + (size_t)(it * 32) * K + k0, As + (it * 4 + w) * 512);
#pragma unroll
    for (int it = 0; it < ITB; ++it)
      gld_lds16(gb + (size_t)(it * 32) * K + k0, Bs + (it * 4 + w) * 512);
    __syncthreads();   // drains vmcnt(0) -> LDS ready for all waves

#pragma unroll
    for (int ks = 0; ks < 2; ++ks) {
      bf16x8 af[MI], bfr[NJ];
#pragma unroll
      for (int i = 0; i < MI; ++i) {
        const int row = wr + i * 16 + (lane & 15);
        af[i] = *(const bf16x8*)&As[row * 64 +
                 (((ks * 4 + (lane >> 4)) ^ (lane & 7)) << 3)];
      }
#pragma unroll
      for (int j = 0; j < NJ; ++j) {
        const int row = wc + j * 16 + (lane & 15);
        bfr[j] = *(const bf16x8*)&Bs[row * 64 +
                  (((ks * 4 + (lane >> 4)) ^ (lane & 7)) << 3)];
      }
#pragma unroll
      for (int i = 0; i < MI; ++i)
#pragma unroll
        for (int j = 0; j < NJ; ++j)
          acc[i][j] = MFMA16(af[i], bfr[j], acc[i][j]);
    }
  }

#pragma unroll
  for (int i = 0; i < MI; ++i) {
#pragma unroll
    for (int j = 0; j < NJ; ++j) {
      const int gcol = nt * BN + wc + j * 16 + (lane & 15);
      const float bv = bias[gcol];
      if (MODE == 0 && t == 2) {
        const int s0g = mt * BM + wr + i * 16 + (lane >> 4) * 4;
        const int b = s0g >> 11, s = s0g & (NS - 1);
        const int h = gcol >> 6, hd = gcol & 63;
        bf16x4 pk = { (bf16)(acc[i][j][0] + bv), (bf16)(acc[i][j][1] + bv),
                      (bf16)(acc[i][j][2] + bv), (bf16)(acc[i][j][3] + bv) };
        *(bf16x4*)&vtp[((size_t)(b * NH + h) * NHD + hd) * NS + s] = pk;
        continue;
      }
#pragma unroll
      for (int r4 = 0; r4 < 4; ++r4) {
        const int grow = mt * BM + wr + i * 16 + (lane >> 4) * 4 + r4;
        float v = acc[i][j][r4] + bv;
        if (MODE == 0) {
          const int b = grow >> 11, s = grow & (NS - 1);
          const int h = gcol >> 6, hd = gcol & 63;
          float pv = __shfl_xor(v, 1);
          const int ii = hd >> 1;
          float c  = fc[(s << 5) + ii];
          float sn = fs[(s << 5) + ii];
          v = ((hd & 1) == 0) ? (v * c - pv * sn) : (pv * sn + v * c);
          if (t == 0) v *= 0.18033688011112042f;   // (1/sqrt(HD)) * log2(e)
          obf[(size_t)t * ((size_t)NM * ND) +
              (((size_t)(b * NH + h) * NS + s) * NHD + hd)] = (bf16)v;
        } else {
          of[(size_t)grow * ND + gcol] = v;
        }
      }
    }
  }
}

// ---------------- one 64-k-tile step for a 16-row q-subtile ---------------
// K/V/P in XOR-swizzled [*][64] LDS (chunk8 ^= row&7). Defer-max (T13):
// skip cross-lane max + rescale unless some lane's tile-max exceeds m+8.
__device__ __forceinline__ void attn_tile(
    const bf16* __restrict__ Ksh, const bf16* __restrict__ Vsh,
    bf16* __restrict__ Pw, const bf16x8* qf, f32x4* o,
    float& m, float& l, int qi, int kk0, bool diag, int qrow, int grp) {
  const int s7 = qrow & 7;
  f32x4 sc[4] = {};
  __builtin_amdgcn_s_setprio(1);
#pragma unroll
  for (int ch = 0; ch < 2; ++ch)
#pragma unroll
    for (int cb = 0; cb < 4; ++cb) {
      bf16x8 kf = *(const bf16x8*)
        &Ksh[(cb * 16 + qrow) * 64 + (((ch * 4 + grp) ^ s7) << 3)];
      sc[cb] = MFMA16(kf, qf[ch], sc[cb]);   // S^T[k][q]
    }
  __builtin_amdgcn_s_setprio(0);

  if (diag) {
#pragma unroll
    for (int cb = 0; cb < 4; ++cb)
#pragma unroll
      for (int r = 0; r < 4; ++r)
        if (kk0 + cb * 16 + grp * 4 + r > qi) sc[cb][r] = -1e30f;
  }

  float a0 = fmaxf(fmaxf(sc[0][0], sc[0][1]), fmaxf(sc[0][2], sc[0][3]));
  float a1 = fmaxf(fmaxf(sc[1][0], sc[1][1]), fmaxf(sc[1][2], sc[1][3]));
  float a2 = fmaxf(fmaxf(sc[2][0], sc[2][1]), fmaxf(sc[2][2], sc[2][3]));
  float a3 = fmaxf(fmaxf(sc[3][0], sc[3][1]), fmaxf(sc[3][2], sc[3][3]));
  float pm = fmaxf(fmaxf(a0, a1), fmaxf(a2, a3));

  if (__any(pm > m + 8.f)) {     // defer-max: rescale only when needed
    float px = fmaxf(pm, __shfl_xor(pm, 16));
    px = fmaxf(px, __shfl_xor(px, 32));
    const float mn = fmaxf(m, px);
    const float scl = exp2f(m - mn);
    m = mn;
    l *= scl;
#pragma unroll
    for (int hb = 0; hb < 4; ++hb)
#pragma unroll
      for (int r = 0; r < 4; ++r) o[hb][r] *= scl;
  }

#pragma unroll
  for (int cb = 0; cb < 4; ++cb) {
    bf16x4 pk;
#pragma unroll
    for (int r = 0; r < 4; ++r) {
      float p = exp2f(sc[cb][r] - m);
      l += p;
      pk[r] = (bf16)p;
    }
    *(bf16x4*)&Pw[qrow * 64 + (((((cb << 1) | (grp >> 1)) ^ s7) << 3)) +
                  ((grp & 1) << 2)] = pk;
  }

  __builtin_amdgcn_s_setprio(1);
#pragma unroll
  for (int ch = 0; ch < 2; ++ch) {
    bf16x8 pa = *(const bf16x8*)
      &Pw[qrow * 64 + (((ch * 4 + grp) ^ s7) << 3)];
#pragma unroll
    for (int hb = 0; hb < 4; ++hb) {
      bf16x8 vf = *(const bf16x8*)
        &Vsh[(hb * 16 + qrow) * 64 + (((ch * 4 + grp) ^ s7) << 3)];
      o[hb] = MFMA16(vf, pa, o[hb]);         // O^T[hd][q]
    }
  }
  __builtin_amdgcn_s_setprio(0);
}

// ---------------- flash attention, causal, 8 waves, k-parity split -------
// r12/r16-proven: double-buffered group-private K/V -> ONE barrier per
// round; XOR-swizzled unpadded LDS (80 KB, 2 blocks/CU); defer-max softmax;
// uniform 17/16-round worklists. grid (32, 16): x = bh, y = j.
// HARD CONSTRAINTS (r13/r15/r17/r19): at (512,4) VGPR cap = 64, exactly
// filled; added live state spills. (512,2) avoids spill but regressed.
// V must flow through the staged-prefetch path (in-round awaited global
// loads drain the K-prefetch vmcnt pipeline).
__global__ __launch_bounds__(512, 4)
void attn_k(const bf16* __restrict__ q, const bf16* __restrict__ k,
            const bf16* __restrict__ vt, bf16* __restrict__ out) {
  __shared__ __align__(16) char smem[81920];
  bf16* KV = (bf16*)smem;                          // [group][buf][K/V][64*64]
  bf16* Pr = (bf16*)(smem + 65536);                // [8 waves][16*64]
  auto MO = (float(*)[2][16][68])smem;             // overlay [4][2][16][68] f32
  auto ML = (float(*)[2][16][2])(smem + 36864);    // overlay [4][2][16][2] f32

  const int tid = threadIdx.x;
  const int w = tid >> 6, lane = tid & 63;
  const int h = w >> 2, wl = w & 3;                // group, pair-index
  const int qrow = lane & 15, grp = lane >> 4;
  const int bh = blockIdx.x, j = blockIdx.y;
  const int b = bh >> 4, hh = bh & (NH - 1);
  const int tA = j, tB = 31 - j;

  const bf16* qb = q + (size_t)bh * NS * NHD;
  const bf16* kb = k + (size_t)bh * NS * NHD;
  const bf16* vb = vt + (size_t)bh * NHD * NS;

  const int nA = (j >= h) ? (((j - h) >> 1) + 1) : 0;   // group's tile-A rounds
  const int nB = (((31 - j) - h) >> 1) + 1;             // group's tile-B rounds
  const int len = nA + nB;                              // 17 (h=0) or 16 (h=1)

  const int q0A = tA * 64 + wl * 16, q0B = tB * 64 + wl * 16;
  bf16x8 qfA[2], qfB[2];
#pragma unroll
  for (int ch = 0; ch < 2; ++ch) {
    qfA[ch] = *(const bf16x8*)&qb[(size_t)(q0A + qrow) * NHD + ch * 32 + grp * 8];
    qfB[ch] = *(const bf16x8*)&qb[(size_t)(q0B + qrow) * NHD + ch * 32 + grp * 8];
  }

  f32x4 oA[4] = {}, oB[4] = {};
  float mA = -1e30f, lA = 0.f, mB = -1e30f, lB = 0.f;

  // group-private staging slots: 256 threads cover 64x64 K + 64x64 V
  const int local = tid & 255;
  const int r0 = local >> 3;                     // rows r0, r0+32
  const int c0 = (local & 7) * 8;                // linear global col
  const int sw = (((local & 7) ^ (r0 & 7)) << 3);  // swizzled LDS col

  bf16* Pw = Pr + w * 1024;
  auto Kb = [&](int buf) { return KV + ((h * 2 + buf) * 2 + 0) * 4096; };
  auto Vb = [&](int buf) { return KV + ((h * 2 + buf) * 2 + 1) * 4096; };

  bf16x8 ka0, ka1, va0, va1;
  auto load_round = [&](int r) {
    const bool isA = r < nA;
    const int kt = isA ? (h + 2 * r) : (h + 2 * (r - nA));
    const int kk0 = kt * 64;
    ka0 = *(const bf16x8*)&kb[(size_t)(kk0 + r0) * NHD + c0];
    ka1 = *(const bf16x8*)&kb[(size_t)(kk0 + r0 + 32) * NHD + c0];
    va0 = *(const bf16x8*)&vb[(size_t)r0 * NS + kk0 + c0];
    va1 = *(const bf16x8*)&vb[(size_t)(r0 + 32) * NS + kk0 + c0];
  };
  auto store_tile = [&](int buf) {
    bf16* Ksc = Kb(buf);
    bf16* Vsc = Vb(buf);
    *(bf16x8*)&Ksc[r0 * 64 + sw]        = ka0;
    *(bf16x8*)&Ksc[(r0 + 32) * 64 + sw] = ka1;   // (r0+32)&7 == r0&7
    *(bf16x8*)&Vsc[r0 * 64 + sw]        = va0;
    *(bf16x8*)&Vsc[(r0 + 32) * 64 + sw] = va1;
  };

  // prologue: tile 0 -> buf 0; issue tile-1 loads
  load_round(0);
  store_tile(0);
  load_round(1);           // len >= 16 always
  block_sync_lds();        // publish buf0 (global loads stay in flight)

  for (int r = 0; r < 17; ++r) {
    const int cur = r & 1;
    const bool act = r < len;
    if (r + 1 < len) store_tile(cur ^ 1);   // tile r+1; its readers synced at r-1
    if (r + 2 < len) load_round(r + 2);     // issue next loads under compute
    if (act) {
      const bool isA = r < nA;
      const int kt = isA ? (h + 2 * r) : (h + 2 * (r - nA));
      if (isA)
        attn_tile(Kb(cur), Vb(cur), Pw, qfA, oA, mA, lA,
                  q0A + qrow, kt * 64, kt == tA, qrow, grp);
      else
        attn_tile(Kb(cur), Vb(cur), Pw, qfB, oB, mB, lB,
                  q0B + qrow, kt * 64, kt == tB, qrow, grp);
    }
    block_sync_lds();      // single barrier: publishes writes, guards WAR
  }

  // reduce l across the 4 lane-groups sharing each q-row
  lA += __shfl_xor(lA, 16); lA += __shfl_xor(lA, 32);
  lB += __shfl_xor(lB, 16); lB += __shfl_xor(lB, 32);

  __syncthreads();   // all LDS traffic done before overlay reuse

  if (h == 1) {      // publish group-1 partials (fp32)
#pragma unroll
    for (int hb = 0; hb < 4; ++hb) {
      *(f32x4*)&MO[wl][0][qrow][hb * 16 + grp * 4] = oA[hb];
      *(f32x4*)&MO[wl][1][qrow][hb * 16 + grp * 4] = oB[hb];
    }
    if (grp == 0) {
      ML[wl][0][qrow][0] = mA; ML[wl][0][qrow][1] = lA;
      ML[wl][1][qrow][0] = mB; ML[wl][1][qrow][1] = lB;
    }
  }
  __syncthreads();

  if (h == 0) {      // merge + store
#pragma unroll
    for (int sub = 0; sub < 2; ++sub) {
      const float m0 = sub ? mB : mA, l0 = sub ? lB : lA;
      const f32x4* o0 = sub ? oB : oA;
      const float m1 = ML[wl][sub][qrow][0], l1 = ML[wl][sub][qrow][1];
      const float mm = fmaxf(m0, m1);
      const float s0 = exp2f(m0 - mm), s1 = exp2f(m1 - mm);
      const float inv = 1.f / (l0 * s0 + l1 * s1);
      const int s = (sub ? q0B : q0A) + qrow;
      bf16* op = out + (size_t)(b * NS + s) * ND + hh * NHD + grp * 4;
#pragma unroll
      for (int hb = 0; hb < 4; ++hb) {
        f32x4 o1 = *(const f32x4*)&MO[wl][sub][qrow][hb * 16 + grp * 4];
        bf16x4 ov = { (bf16)((o0[hb][0] * s0 + o1[0] * s1) * inv),
                      (bf16)((o0[hb][1] * s0 + o1[1] * s1) * inv),
                      (bf16)((o0[hb][2] * s0 + o1[2] * s1) * inv),
                      (bf16)((o0[hb][3] * s0 + o1[3] * s1) * inv) };
        *(bf16x4*)&op[hb * 16] = ov;
      }
    }
  }
}

// -------------------------------------------------------------------------
extern "C" void kernel_launch(void* const* d_in, const int* in_sizes, int n_in,
                              void* d_out, int out_size, void* d_ws, size_t ws_size,
                              hipStream_t stream) {
  const float* Q  = (const float*)d_in[0];
  const float* K  = (const float*)d_in[1];
  const float* V  = (const float*)d_in[2];
  // d_in[3] = mask (causal, known analytically -> unused)
  const float* fc = (const float*)d_in[4];
  const float* fs = (const float*)d_in[5];
  const float* wq = (const float*)d_in[6];
  const float* bq = (const float*)d_in[7];
  const float* wk = (const float*)d_in[8];
  const float* bk = (const float*)d_in[9];
  const float* wv = (const float*)d_in[10];
  const float* bv = (const float*)d_in[11];
  const float* wo = (const float*)d_in[12];
  const float* bo = (const float*)d_in[13];
  float* out = (float*)d_out;
  bf16* ws = (bf16*)d_ws;

  const size_t MB_ = 1024 * 1024;  // elements
  bf16* Qbf  = ws;                     // 3 x 4M elems (Q,K,V bf16)
  bf16* Wqkv = ws + 12 * MB_;          // 3 x 1M (wq, wk, wv)
  bf16* Wo   = ws + 15 * MB_;          // 1M
  bf16* qp   = ws + 16 * MB_;          // q' [BH,S,HD] 4M
  bf16* kp   = ws + 20 * MB_;          // k' 4M
  bf16* vtp  = ws + 28 * MB_;          // v transposed [BH,HD,S] 4M (direct)
  bf16* aout = ws + 32 * MB_;          // attention output [M, D] 4M

  cvt7<<<dim3(4096, 7), 256, 0, stream>>>(Q, K, V, wq, wk, wv, wo, ws);

  gemm_nt<0><<<1536, 256, 0, stream>>>(Qbf, Wqkv, bq, bk, bv, fc, fs,
                                       qp, vtp, nullptr);

  attn_k<<<dim3(32, 16), 512, 0, stream>>>(qp, kp, vtp, aout);

  gemm_nt<1><<<1024, 256, 0, stream>>>(aout, Wo, bo, bo, bo, fc, fs,
                                       nullptr, nullptr, out);
}